// Round 14
// baseline (111.821 us; speedup 1.0000x reference)
//
#include <hip/hip_runtime.h>
#include <hip/hip_bf16.h>

// N=4,B=8,T=2,E=1024,H=16,D=64,S=2048,L=1024
#define NB_  32
#define T_   2
#define E_   1024
#define H_   16
#define D_   64
#define S_   2048
#define L_   1024
#define TOT_ (S_ + L_ + T_)   // 3074

#define PCH_  16              // prefix chunks per (n,h): 128 pos each
#define PLEN_ (S_ / PCH_)     // 128
#define NT_   8               // tiles per prefix unit (16 pos each)
#define PFXU_ (4 * H_ * PCH_) // 1024 prefix units

// cur streaming kernel geometry
#define CTILE_ 32             // positions per tile
#define NTIL_  (L_ / CTILE_)  // 32 tiles
#define RING_  3              // LDS ring depth (tiles in flight)
#define SLOTF_ 4096           // floats per slot (K 2048 | V 2048)
#define MOFF_  (RING_ * SLOTF_)  // mask buffer offset (12288)

#define LOG2E_ 1.4426950408889634f
#define QS_ (0.125f * LOG2E_)

#define GLOAD_LDS16(g, l) __builtin_amdgcn_global_load_lds( \
    (const __attribute__((address_space(1))) void*)(g), \
    (__attribute__((address_space(3))) void*)(l), 16, 0, 0)

// ---------------------------------------------------------------------------
// QKV: out[64][3072] = hidden[64][1024] @ Wcat^T + bias. (R8 proven)
// ---------------------------------------------------------------------------
__global__ __launch_bounds__(256) void qkv_kernel(
    const float* __restrict__ hidden,
    const float* __restrict__ Wq, const float* __restrict__ bq,
    const float* __restrict__ Wk, const float* __restrict__ bk,
    const float* __restrict__ Wv, const float* __restrict__ bv,
    float* __restrict__ qT,      // [1024][64]
    float* __restrict__ knew,    // [NB][H][T][D]
    float* __restrict__ vnew)
{
    __shared__ float ldsT[128 * 65];
    __shared__ float wlds[8 * 128];
    const int tid  = threadIdx.x;
    const int wave = tid >> 6;
    const int lane = tid & 63;
    const int eg0  = blockIdx.x * 8;
    const int mat  = eg0 >> 10;
    const int e0   = eg0 & 1023;
    int c0 = wave * 2;
    c0 = __builtin_amdgcn_readfirstlane(c0);

    const float* W    = (mat == 0) ? Wq : (mat == 1) ? Wk : Wv;
    const float* bias = (mat == 0) ? bq : (mat == 1) ? bk : bv;

    float aA0 = 0.f, aB0 = 0.f, aA1 = 0.f, aB1 = 0.f;

    for (int k0 = 0; k0 < 1024; k0 += 128) {
        __syncthreads();
        #pragma unroll
        for (int i = 0; i < 32; i++) {
            int f = i * 256 + tid;
            int r = f >> 7;
            int c = f & 127;
            ldsT[c * 65 + r] = hidden[r * 1024 + k0 + c];
        }
        {
            int wr = tid >> 5;
            int wc = (tid & 31) * 4;
            *reinterpret_cast<float4*>(&wlds[wr * 128 + wc]) =
                *reinterpret_cast<const float4*>(&W[(size_t)(e0 + wr) * 1024 + k0 + wc]);
        }
        __syncthreads();

        for (int kk = 0; kk < 128; kk += 4) {
            float h0 = ldsT[(kk + 0) * 65 + lane];
            float h1 = ldsT[(kk + 1) * 65 + lane];
            float h2 = ldsT[(kk + 2) * 65 + lane];
            float h3 = ldsT[(kk + 3) * 65 + lane];
            float4 w0 = *reinterpret_cast<const float4*>(&wlds[(c0 + 0) * 128 + kk]);
            float4 w1 = *reinterpret_cast<const float4*>(&wlds[(c0 + 1) * 128 + kk]);
            aA0 = fmaf(h0, w0.x, aA0); aA0 = fmaf(h1, w0.y, aA0);
            aB0 = fmaf(h2, w0.z, aB0); aB0 = fmaf(h3, w0.w, aB0);
            aA1 = fmaf(h0, w1.x, aA1); aA1 = fmaf(h1, w1.y, aA1);
            aB1 = fmaf(h2, w1.z, aB1); aB1 = fmaf(h3, w1.w, aB1);
        }
    }

    const int r = lane;
    #pragma unroll
    for (int j = 0; j < 2; j++) {
        int e_in = e0 + c0 + j;
        float val = ((j == 0) ? (aA0 + aB0) : (aA1 + aB1)) + bias[e_in];
        if (mat == 0) {
            qT[e_in * 64 + r] = val;
        } else {
            int nb = r >> 1, t = r & 1, h = e_in >> 6, d = e_in & 63;
            float* dst = (mat == 1) ? knew : vnew;
            dst[((nb * H_ + h) * T_ + t) * D_ + d] = val;
        }
    }
}

// ---------------------------------------------------------------------------
// Cur streaming partial: 512 blocks x 256 thr, one (nb,h) per block, all
// L+T positions. K/V staged via global_load_lds into a 3-slot LDS ring of
// 32-pos tiles. Deep pipeline with RAW s_barrier + counted inline-asm
// s_waitcnt vmcnt(8) (T3/T4, m201 pattern): 2-3 tiles' loads stay in flight
// ACROSS barriers (~8-12KB/wave outstanding) instead of the vmcnt(0)-per-
// iteration drain that pinned every prior variant at ~2.8 TB/s even L3-hot.
// Masks pre-staged in LDS so no stray VMEM ops disturb the vmcnt counting.
// ---------------------------------------------------------------------------
__global__ __launch_bounds__(256) void cur_stream_kernel(
    const float* __restrict__ mask,   // [NB][TOT_]
    const float* __restrict__ pk,     // [NB][H][L][D]
    const float* __restrict__ pv,
    const float* __restrict__ qT,     // [1024][64]
    const float* __restrict__ knew,   // [NB][H][T][D]
    const float* __restrict__ vnew,
    float* __restrict__ cur_ctx,      // [512][2][64]
    float* __restrict__ cur_l)        // [512][2]
{
    __shared__ float smem[MOFF_ + 1056];   // ring 12288 | mask 1056
    const int tid = threadIdx.x;
    const int bid = blockIdx.x;
    const int nb  = bid >> 4;
    const int h   = bid & 15;
    const int g   = tid >> 4;     // group 0..15
    const int l16 = tid & 15;
    const int d0  = l16 * 4;

    float qf0[4], qf1[4];
    #pragma unroll
    for (int j = 0; j < 4; j++) {
        const float* qb = qT + (h * 64 + d0 + j) * 64 + nb * 2;
        qf0[j] = qb[0] * QS_;
        qf1[j] = qb[1] * QS_;
    }

    const float* pk_b = pk + ((nb * H_ + h) * (size_t)L_) * D_;
    const float* pv_b = pv + ((nb * H_ + h) * (size_t)L_) * D_;
    const float* mrow = mask + nb * TOT_ + S_;

    // stage masks (L+T entries) into LDS once; syncthreads drains these loads
    for (int i = tid; i < L_ + T_; i += 256)
        smem[MOFF_ + i] = mrow[i] * LOG2E_;
    __syncthreads();

    float l0 = 0.f, l1 = 0.f;
    float a0[4] = {0.f,0.f,0.f,0.f};
    float a1[4] = {0.f,0.f,0.f,0.f};

    auto stage_tile = [&](int t, int s) {
        const float* kt = pk_b + (size_t)t * (CTILE_ * D_);
        const float* vt = pv_b + (size_t)t * (CTILE_ * D_);
        GLOAD_LDS16(kt + tid * 4,        &smem[s * SLOTF_ + tid * 4]);
        GLOAD_LDS16(kt + 1024 + tid * 4, &smem[s * SLOTF_ + 1024 + tid * 4]);
        GLOAD_LDS16(vt + tid * 4,        &smem[s * SLOTF_ + 2048 + tid * 4]);
        GLOAD_LDS16(vt + 1024 + tid * 4, &smem[s * SLOTF_ + 3072 + tid * 4]);
    };

    auto compute_tile = [&](int t, int s) {
        #pragma unroll
        for (int sub = 0; sub < 2; sub++) {
            const int pl = sub * 16 + g;          // tile-local position
            float4 kf = *reinterpret_cast<const float4*>(
                &smem[s * SLOTF_ + pl * 64 + d0]);
            float s0 = fmaf(qf0[0],kf.x, qf0[1]*kf.y) + fmaf(qf0[2],kf.z, qf0[3]*kf.w);
            float s1 = fmaf(qf1[0],kf.x, qf1[1]*kf.y) + fmaf(qf1[2],kf.z, qf1[3]*kf.w);
            #pragma unroll
            for (int off = 1; off < 16; off <<= 1) {
                s0 += __shfl_xor(s0, off, 64);
                s1 += __shfl_xor(s1, off, 64);
            }
            float mC = smem[MOFF_ + t * CTILE_ + pl];
            float e0 = exp2f(s0 + mC);
            float e1 = exp2f(s1 + mC);
            l0 += e0; l1 += e1;
            float4 vf = *reinterpret_cast<const float4*>(
                &smem[s * SLOTF_ + 2048 + pl * 64 + d0]);
            a0[0] += e0 * vf.x; a0[1] += e0 * vf.y; a0[2] += e0 * vf.z; a0[3] += e0 * vf.w;
            a1[0] += e1 * vf.x; a1[1] += e1 * vf.y; a1[2] += e1 * vf.z; a1[3] += e1 * vf.w;
        }
    };

    // prologue: tiles 0,1,2 -> slots 0,1,2 (12 gloads/thread in flight)
    stage_tile(0, 0);
    stage_tile(1, 1);
    stage_tile(2, 2);

    // steady state: gate vmcnt(8) = RING_-1 tiles x 4 loads still in flight
    #pragma unroll 1
    for (int t = 0; t < NTIL_ - 3; t++) {       // t = 0..28
        asm volatile("s_waitcnt vmcnt(8)" ::: "memory");
        __builtin_amdgcn_sched_barrier(0);
        __builtin_amdgcn_s_barrier();           // tile t landed for ALL threads
        compute_tile(t, t % RING_);
        __builtin_amdgcn_s_barrier();           // all done reading slot
        stage_tile(t + 3, t % RING_);
    }
    // tail: t = 29, 30, 31 (no more staging; shrink the gate)
    asm volatile("s_waitcnt vmcnt(8)" ::: "memory");
    __builtin_amdgcn_sched_barrier(0);
    __builtin_amdgcn_s_barrier();
    compute_tile(29, 29 % RING_);
    __builtin_amdgcn_s_barrier();
    asm volatile("s_waitcnt vmcnt(4)" ::: "memory");
    __builtin_amdgcn_sched_barrier(0);
    __builtin_amdgcn_s_barrier();
    compute_tile(30, 30 % RING_);
    __builtin_amdgcn_s_barrier();
    asm volatile("s_waitcnt vmcnt(0)" ::: "memory");
    __builtin_amdgcn_sched_barrier(0);
    __builtin_amdgcn_s_barrier();
    compute_tile(31, 31 % RING_);

    // 2 new tokens (global direct; after all gates)
    if (g < 2) {
        const float* kn_b = knew + (nb * H_ + h) * (T_ * D_);
        const float* vn_b = vnew + (nb * H_ + h) * (T_ * D_);
        float4 kfn = *reinterpret_cast<const float4*>(kn_b + g * D_ + d0);
        float s0 = fmaf(qf0[0],kfn.x, qf0[1]*kfn.y) + fmaf(qf0[2],kfn.z, qf0[3]*kfn.w);
        float s1 = fmaf(qf1[0],kfn.x, qf1[1]*kfn.y) + fmaf(qf1[2],kfn.z, qf1[3]*kfn.w);
        #pragma unroll
        for (int off = 1; off < 16; off <<= 1) {
            s0 += __shfl_xor(s0, off, 64);
            s1 += __shfl_xor(s1, off, 64);
        }
        float mC = smem[MOFF_ + L_ + g];
        float e0 = exp2f(s0 + mC);
        float e1 = exp2f(s1 + mC);
        l0 += e0; l1 += e1;
        float4 vfn = *reinterpret_cast<const float4*>(vn_b + g * D_ + d0);
        a0[0] += e0 * vfn.x; a0[1] += e0 * vfn.y; a0[2] += e0 * vfn.z; a0[3] += e0 * vfn.w;
        a1[0] += e1 * vfn.x; a1[1] += e1 * vfn.y; a1[2] += e1 * vfn.z; a1[3] += e1 * vfn.w;
    }

    __syncthreads();   // pipeline over; reuse ring as reduction scratch
    #pragma unroll
    for (int j = 0; j < 4; j++) {
        smem[g * 128 + d0 + j]      = a0[j];
        smem[g * 128 + 64 + d0 + j] = a1[j];
    }
    if (l16 == 0) { smem[2048 + g * 2] = l0; smem[2048 + g * 2 + 1] = l1; }
    __syncthreads();

    if (tid < 128) {
        int t = tid >> 6, d = tid & 63;
        float s = 0.f, l = 0.f;
        for (int g2 = 0; g2 < 16; g2++) {
            s += smem[g2 * 128 + t * 64 + d];
            l += smem[2048 + g2 * 2 + t];
        }
        cur_ctx[(bid * 2 + t) * 64 + d] = s;   // unnormalized
        if (d == 0) cur_l[bid * 2 + t] = l;
    }
}

// ---------------------------------------------------------------------------
// Prefix partial: 1024 blocks x 256 thr (R8 proven, L3-hot, fast).
// ---------------------------------------------------------------------------
__global__ __launch_bounds__(256) void pfx_partial_kernel(
    const float* __restrict__ mask,   // [NB][TOT_]
    const float* __restrict__ pfx_k,  // [N][H][S][D]
    const float* __restrict__ pfx_v,
    const float* __restrict__ qT,     // [1024][64]
    float* __restrict__ pfx_ctx,      // [PFXU_][16][64]
    float* __restrict__ pfx_l)        // [PFXU_][16]
{
    __shared__ float smem[4160];
    const int tid = threadIdx.x;

    const int v     = blockIdx.x;
    const int n     = v >> 8;             // /(H_*PCH_)=256
    const int h     = (v >> 4) & 15;
    const int chunk = v & 15;
    const int wv    = tid >> 6;
    const int lane  = tid & 63;
    const int r     = lane & 15;          // row = beam*2 + t
    const int c     = lane >> 4;          // dim quarter

    float qreg[16];
    const float* qbase = qT + (h * 64 + c * 16) * 64 + (n * 16 + r);
    #pragma unroll
    for (int u = 0; u < 16; u++) qreg[u] = qbase[u * 64] * QS_;

    const size_t pos0 = (size_t)(n * H_ + h) * S_ + chunk * PLEN_;
    const float* kb = pfx_k + pos0 * D_;           // tile t: +t*16*64
    const float* vb = pfx_v + pos0 * D_;
    const float* mrow = mask + (n * 8 + (r >> 1)) * TOT_ + chunk * PLEN_;

    float ctx[16];
    #pragma unroll
    for (int u = 0; u < 16; u++) ctx[u] = 0.f;
    float lsum = 0.f;

    GLOAD_LDS16(kb + tid * 4, &smem[tid * 4]);
    GLOAD_LDS16(vb + tid * 4, &smem[1024 + tid * 4]);

    #pragma unroll 1
    for (int t = 0; t < NT_; t++) {
        const int bufo = (t & 1) * 2048;
        __syncthreads();

        float mreg[4];
        #pragma unroll
        for (int j = 0; j < 4; j++)
            mreg[j] = mrow[t * 16 + wv * 4 + j] * LOG2E_;

        if (t < NT_ - 1) {
            const int nbo = ((t + 1) & 1) * 2048;
            const float* kn = kb + (size_t)(t + 1) * 16 * 64;
            const float* vn = vb + (size_t)(t + 1) * 16 * 64;
            GLOAD_LDS16(kn + tid * 4, &smem[nbo + tid * 4]);
            GLOAD_LDS16(vn + tid * 4, &smem[nbo + 1024 + tid * 4]);
        }

        #pragma unroll
        for (int j = 0; j < 4; j++) {
            const int pp = wv * 4 + j;
            const float4* kq = reinterpret_cast<const float4*>(
                &smem[bufo + pp * 64 + c * 16]);
            float4 k0 = kq[0], k1 = kq[1], k2 = kq[2], k3 = kq[3];
            float sA = qreg[0]*k0.x;  sA = fmaf(qreg[1],k0.y,sA);
            sA = fmaf(qreg[2],k0.z,sA); sA = fmaf(qreg[3],k0.w,sA);
            float sB = qreg[4]*k1.x;  sB = fmaf(qreg[5],k1.y,sB);
            sB = fmaf(qreg[6],k1.z,sB); sB = fmaf(qreg[7],k1.w,sB);
            float sC = qreg[8]*k2.x;  sC = fmaf(qreg[9],k2.y,sC);
            sC = fmaf(qreg[10],k2.z,sC); sC = fmaf(qreg[11],k2.w,sC);
            float sD = qreg[12]*k3.x; sD = fmaf(qreg[13],k3.y,sD);
            sD = fmaf(qreg[14],k3.z,sD); sD = fmaf(qreg[15],k3.w,sD);
            float s = (sA + sB) + (sC + sD);
            s += __shfl_xor(s, 16, 64);
            s += __shfl_xor(s, 32, 64);
            float e = exp2f(s + mreg[j]);
            lsum += e;
            const float4* vq = reinterpret_cast<const float4*>(
                &smem[bufo + 1024 + pp * 64 + c * 16]);
            float4 v0 = vq[0], v1 = vq[1], v2 = vq[2], v3 = vq[3];
            ctx[0]  += e * v0.x; ctx[1]  += e * v0.y; ctx[2]  += e * v0.z; ctx[3]  += e * v0.w;
            ctx[4]  += e * v1.x; ctx[5]  += e * v1.y; ctx[6]  += e * v1.z; ctx[7]  += e * v1.w;
            ctx[8]  += e * v2.x; ctx[9]  += e * v2.y; ctx[10] += e * v2.z; ctx[11] += e * v2.w;
            ctx[12] += e * v3.x; ctx[13] += e * v3.y; ctx[14] += e * v3.z; ctx[15] += e * v3.w;
        }
    }

    __syncthreads();
    const int base = wv * 1024 + r * 64 + c * 16;
    #pragma unroll
    for (int u = 0; u < 16; u += 4)
        *reinterpret_cast<float4*>(&smem[base + u]) =
            make_float4(ctx[u], ctx[u+1], ctx[u+2], ctx[u+3]);
    if (c == 0) smem[4096 + wv * 16 + r] = lsum;
    __syncthreads();

    const int pc = (n * H_ + h) * PCH_ + chunk;
    for (int e = tid; e < 1024; e += 256) {
        float s = smem[e] + smem[1024 + e] + smem[2048 + e] + smem[3072 + e];
        pfx_ctx[pc * 1024 + e] = s;
    }
    if (tid < 16) {
        float l = smem[4096 + tid] + smem[4096 + 16 + tid]
                + smem[4096 + 32 + tid] + smem[4096 + 48 + tid];
        pfx_l[pc * 16 + tid] = l;
    }
}

// ---------------------------------------------------------------------------
// Combine: out = (cur_ctx + sum of 16 prefix ctx partials) / (sum of l)
// ---------------------------------------------------------------------------
__global__ __launch_bounds__(256) void combine_kernel(
    const float* __restrict__ cur_ctx, const float* __restrict__ cur_l,
    const float* __restrict__ pfx_ctx, const float* __restrict__ pfx_l,
    float* __restrict__ out)
{
    const int row = blockIdx.x >> 2;      // nb*2+t
    const int qtr = blockIdx.x & 3;
    const int nb  = row >> 1, t = row & 1;
    const int n   = nb >> 3;
    const int r   = (nb & 7) * 2 + t;
    const int e   = qtr * 256 + threadIdx.x;   // h*64+d
    const int h   = e >> 6, d = e & 63;
    const int b   = nb * 16 + h;

    float val = cur_ctx[(b * 2 + t) * 64 + d];
    float l   = cur_l[b * 2 + t];
    #pragma unroll
    for (int ch = 0; ch < PCH_; ch++) {
        int pc = (n * H_ + h) * PCH_ + ch;
        val += pfx_ctx[pc * 1024 + r * 64 + d];
        l   += pfx_l[pc * 16 + r];
    }
    out[row * 1024 + e] = val / l;
}

extern "C" void kernel_launch(void* const* d_in, const int* in_sizes, int n_in,
                              void* d_out, int out_size, void* d_ws, size_t ws_size,
                              hipStream_t stream) {
    const float* hidden = (const float*)d_in[0];
    const float* mask   = (const float*)d_in[1];
    const float* pfxk   = (const float*)d_in[2];
    const float* pfxv   = (const float*)d_in[3];
    const float* pk     = (const float*)d_in[4];
    const float* pv     = (const float*)d_in[5];
    const float* Wq     = (const float*)d_in[6];
    const float* bq     = (const float*)d_in[7];
    const float* Wk     = (const float*)d_in[8];
    const float* bk     = (const float*)d_in[9];
    const float* Wv     = (const float*)d_in[10];
    const float* bv     = (const float*)d_in[11];

    float* qT      = (float*)d_ws;             // 65536
    float* knew    = qT + 65536;               // 65536
    float* vnew    = knew + 65536;             // 65536
    float* cur_ctx = vnew + 65536;             // 512*2*64 = 65536
    float* cur_l   = cur_ctx + 65536;          // 1024
    float* pfx_ctx = cur_l + 1024;             // 1024*1024 = 1048576
    float* pfx_l   = pfx_ctx + 1048576;        // 16384

    qkv_kernel<<<384, 256, 0, stream>>>(hidden, Wq, bq, Wk, bk, Wv, bv,
                                        qT, knew, vnew);
    cur_stream_kernel<<<512, 256, 0, stream>>>(
        mask, pk, pv, qT, knew, vnew, cur_ctx, cur_l);
    pfx_partial_kernel<<<PFXU_, 256, 0, stream>>>(
        mask, pfxk, pfxv, qT, pfx_ctx, pfx_l);
    combine_kernel<<<256, 256, 0, stream>>>(cur_ctx, cur_l, pfx_ctx, pfx_l,
                                            (float*)d_out);
}

// Round 15
// 107.101 us; speedup vs baseline: 1.0441x; 1.0441x over previous
//
#include <hip/hip_runtime.h>
#include <hip/hip_bf16.h>

// N=4,B=8,T=2,E=1024,H=16,D=64,S=2048,L=1024
#define NB_  32
#define T_   2
#define E_   1024
#define H_   16
#define D_   64
#define S_   2048
#define L_   1024
#define TOT_ (S_ + L_ + T_)   // 3074

#define PCH_  16              // prefix chunks per (n,h): 128 pos each
#define PLEN_ (S_ / PCH_)     // 128
#define NT_   8               // tiles per prefix unit (16 pos each)
#define PFXU_ (4 * H_ * PCH_) // 1024 prefix units

// cur GEMM-style kernel geometry
#define CCH2_  4              // chunks per (nb,h) -> 2048 blocks, 4/CU
#define CPOS2_ 256            // positions per chunk
#define PERW_  2144           // per-wave LDS floats: KT 1088 | V 1024 | eb 32
#define VOFF_  1088
#define EOFF_  2112
#define MOFF2_ (4 * PERW_)    // 8576: mask slice (258 -> 264)
#define QOFF_  (MOFF2_ + 264) // 8840: q pairs (128)
#define TBOFF_ (QOFF_ + 128)  // 8968: tail ctx [2pos][2t][64]
#define LTOFF_ (TBOFF_ + 256) // 9224: tail l [2pos][2t]
#define SMEM2_ 9232

#define LOG2E_ 1.4426950408889634f
#define QS_ (0.125f * LOG2E_)

#define GLOAD_LDS16(g, l) __builtin_amdgcn_global_load_lds( \
    (const __attribute__((address_space(1))) void*)(g), \
    (__attribute__((address_space(3))) void*)(l), 16, 0, 0)

// ---------------------------------------------------------------------------
// QKV: out[64][3072] = hidden[64][1024] @ Wcat^T + bias. (R8 proven)
// ---------------------------------------------------------------------------
__global__ __launch_bounds__(256) void qkv_kernel(
    const float* __restrict__ hidden,
    const float* __restrict__ Wq, const float* __restrict__ bq,
    const float* __restrict__ Wk, const float* __restrict__ bk,
    const float* __restrict__ Wv, const float* __restrict__ bv,
    float* __restrict__ qT,      // [1024][64]
    float* __restrict__ knew,    // [NB][H][T][D]
    float* __restrict__ vnew)
{
    __shared__ float ldsT[128 * 65];
    __shared__ float wlds[8 * 128];
    const int tid  = threadIdx.x;
    const int wave = tid >> 6;
    const int lane = tid & 63;
    const int eg0  = blockIdx.x * 8;
    const int mat  = eg0 >> 10;
    const int e0   = eg0 & 1023;
    int c0 = wave * 2;
    c0 = __builtin_amdgcn_readfirstlane(c0);

    const float* W    = (mat == 0) ? Wq : (mat == 1) ? Wk : Wv;
    const float* bias = (mat == 0) ? bq : (mat == 1) ? bk : bv;

    float aA0 = 0.f, aB0 = 0.f, aA1 = 0.f, aB1 = 0.f;

    for (int k0 = 0; k0 < 1024; k0 += 128) {
        __syncthreads();
        #pragma unroll
        for (int i = 0; i < 32; i++) {
            int f = i * 256 + tid;
            int r = f >> 7;
            int c = f & 127;
            ldsT[c * 65 + r] = hidden[r * 1024 + k0 + c];
        }
        {
            int wr = tid >> 5;
            int wc = (tid & 31) * 4;
            *reinterpret_cast<float4*>(&wlds[wr * 128 + wc]) =
                *reinterpret_cast<const float4*>(&W[(size_t)(e0 + wr) * 1024 + k0 + wc]);
        }
        __syncthreads();

        for (int kk = 0; kk < 128; kk += 4) {
            float h0 = ldsT[(kk + 0) * 65 + lane];
            float h1 = ldsT[(kk + 1) * 65 + lane];
            float h2 = ldsT[(kk + 2) * 65 + lane];
            float h3 = ldsT[(kk + 3) * 65 + lane];
            float4 w0 = *reinterpret_cast<const float4*>(&wlds[(c0 + 0) * 128 + kk]);
            float4 w1 = *reinterpret_cast<const float4*>(&wlds[(c0 + 1) * 128 + kk]);
            aA0 = fmaf(h0, w0.x, aA0); aA0 = fmaf(h1, w0.y, aA0);
            aB0 = fmaf(h2, w0.z, aB0); aB0 = fmaf(h3, w0.w, aB0);
            aA1 = fmaf(h0, w1.x, aA1); aA1 = fmaf(h1, w1.y, aA1);
            aB1 = fmaf(h2, w1.z, aB1); aB1 = fmaf(h3, w1.w, aB1);
        }
    }

    const int r = lane;
    #pragma unroll
    for (int j = 0; j < 2; j++) {
        int e_in = e0 + c0 + j;
        float val = ((j == 0) ? (aA0 + aB0) : (aA1 + aB1)) + bias[e_in];
        if (mat == 0) {
            qT[e_in * 64 + r] = val;
        } else {
            int nb = r >> 1, t = r & 1, h = e_in >> 6, d = e_in & 63;
            float* dst = (mat == 1) ? knew : vnew;
            dst[((nb * H_ + h) * T_ + t) * D_ + d] = val;
        }
    }
}

// ---------------------------------------------------------------------------
// Cur GEMM-style partial: 2048 blocks x 256 thr; block = (nb,h,chunk of 256
// positions). NO per-position cross-lane reduction (the ~100us invariant
// across R5-R14 was the 8-shfl+exp2 serial chain per 256B, unchanged by
// occupancy/residency/staging). New shape, per wave-private 16-pos tile:
//   stage: K transposed+padded KT[64][17] (reg-staged, 2-way banks max),
//          V linear [16][64]; next tile prefetched into 8 float4 regs.
//   scores: lane=(pos,dquarter): 16 LDS FMAs + ONLY 2 shfl_xor per 16 pos
//           (64x fewer cross-lane ops), 2 exp2/tile.
//   PV: lane=dim, e via LDS broadcast, conflict-free V reads, pure FMA.
// Zero barriers in the main loop (wave-private regions).
// ---------------------------------------------------------------------------
__global__ __launch_bounds__(256) void cur_gemm_kernel(
    const float* __restrict__ mask,   // [NB][TOT_]
    const float* __restrict__ pk,     // [NB][H][L][D]
    const float* __restrict__ pv,
    const float* __restrict__ qT,     // [1024][64]
    const float* __restrict__ knew,   // [NB][H][T][D]
    const float* __restrict__ vnew,
    float* __restrict__ cur_ctx,      // [2048][2][64]
    float* __restrict__ cur_l)        // [2048][2]
{
    __shared__ float smem[SMEM2_];
    const int tid   = threadIdx.x;
    const int u     = blockIdx.x;      // b*4 + chunk
    const int b     = u >> 2;          // nb*16+h
    const int chunk = u & 3;
    const int nb    = b >> 4;
    const int h     = b & 15;
    const int w     = tid >> 6;
    const int l     = tid & 63;
    const int p16   = l & 15;
    const int dq    = l >> 4;

    const float* pk_b = pk + ((nb * H_ + h) * (size_t)L_ + chunk * CPOS2_) * D_;
    const float* pv_b = pv + ((nb * H_ + h) * (size_t)L_ + chunk * CPOS2_) * D_;
    const float* mrow = mask + nb * TOT_ + S_ + chunk * CPOS2_;

    // stage mask slice (+2 new-token entries for chunk 3) and q pairs
    for (int i = tid; i < CPOS2_; i += 256)
        smem[MOFF2_ + i] = mrow[i] * LOG2E_;
    if (chunk == 3 && tid < 2)
        smem[MOFF2_ + CPOS2_ + tid] = mrow[CPOS2_ + tid] * LOG2E_;
    if (tid < 64) {
        float q0 = qT[(h * 64 + tid) * 64 + nb * 2];
        float q1 = qT[(h * 64 + tid) * 64 + nb * 2 + 1];
        smem[QOFF_ + tid * 2]     = q0 * QS_;
        smem[QOFF_ + tid * 2 + 1] = q1 * QS_;
    }
    __syncthreads();

    float* WR = smem + w * PERW_;

    float ctx0 = 0.f, ctx1 = 0.f, lw0 = 0.f, lw1 = 0.f;
    float4 kr0, kr1, kr2, kr3, vr0, vr1, vr2, vr3;

    // prefetch tile w (wave w owns tiles w, w+4, w+8, w+12)
    {
        const float* kt = pk_b + (size_t)w * 1024;
        const float* vt = pv_b + (size_t)w * 1024;
        kr0 = *reinterpret_cast<const float4*>(kt + 0   + l * 4);
        kr1 = *reinterpret_cast<const float4*>(kt + 256 + l * 4);
        kr2 = *reinterpret_cast<const float4*>(kt + 512 + l * 4);
        kr3 = *reinterpret_cast<const float4*>(kt + 768 + l * 4);
        vr0 = *reinterpret_cast<const float4*>(vt + 0   + l * 4);
        vr1 = *reinterpret_cast<const float4*>(vt + 256 + l * 4);
        vr2 = *reinterpret_cast<const float4*>(vt + 512 + l * 4);
        vr3 = *reinterpret_cast<const float4*>(vt + 768 + l * 4);
    }

    #pragma unroll 1
    for (int i = 0; i < 4; i++) {
        const int tile = w + i * 4;

        // ---- store current tile regs to LDS (K transposed+padded, V linear)
        {
            const int d0 = (l & 15) * 4;
            const int pb = l >> 4;              // 0..3
            WR[(d0+0)*17 + (pb+ 0)] = kr0.x; WR[(d0+1)*17 + (pb+ 0)] = kr0.y;
            WR[(d0+2)*17 + (pb+ 0)] = kr0.z; WR[(d0+3)*17 + (pb+ 0)] = kr0.w;
            WR[(d0+0)*17 + (pb+ 4)] = kr1.x; WR[(d0+1)*17 + (pb+ 4)] = kr1.y;
            WR[(d0+2)*17 + (pb+ 4)] = kr1.z; WR[(d0+3)*17 + (pb+ 4)] = kr1.w;
            WR[(d0+0)*17 + (pb+ 8)] = kr2.x; WR[(d0+1)*17 + (pb+ 8)] = kr2.y;
            WR[(d0+2)*17 + (pb+ 8)] = kr2.z; WR[(d0+3)*17 + (pb+ 8)] = kr2.w;
            WR[(d0+0)*17 + (pb+12)] = kr3.x; WR[(d0+1)*17 + (pb+12)] = kr3.y;
            WR[(d0+2)*17 + (pb+12)] = kr3.z; WR[(d0+3)*17 + (pb+12)] = kr3.w;
            *reinterpret_cast<float4*>(&WR[VOFF_ + (pb+ 0)*64 + d0]) = vr0;
            *reinterpret_cast<float4*>(&WR[VOFF_ + (pb+ 4)*64 + d0]) = vr1;
            *reinterpret_cast<float4*>(&WR[VOFF_ + (pb+ 8)*64 + d0]) = vr2;
            *reinterpret_cast<float4*>(&WR[VOFF_ + (pb+12)*64 + d0]) = vr3;
        }

        // ---- prefetch next tile
        if (i < 3) {
            const float* kt = pk_b + (size_t)(tile + 4) * 1024;
            const float* vt = pv_b + (size_t)(tile + 4) * 1024;
            kr0 = *reinterpret_cast<const float4*>(kt + 0   + l * 4);
            kr1 = *reinterpret_cast<const float4*>(kt + 256 + l * 4);
            kr2 = *reinterpret_cast<const float4*>(kt + 512 + l * 4);
            kr3 = *reinterpret_cast<const float4*>(kt + 768 + l * 4);
            vr0 = *reinterpret_cast<const float4*>(vt + 0   + l * 4);
            vr1 = *reinterpret_cast<const float4*>(vt + 256 + l * 4);
            vr2 = *reinterpret_cast<const float4*>(vt + 512 + l * 4);
            vr3 = *reinterpret_cast<const float4*>(vt + 768 + l * 4);
        }

        // ---- scores: lane (p16, dq) computes quarter-dot for position p16
        float s0 = 0.f, s1 = 0.f;
        #pragma unroll
        for (int dd = 0; dd < 16; dd++) {
            float  kv = WR[(dq * 16 + dd) * 17 + p16];
            float2 q  = *reinterpret_cast<const float2*>(
                            &smem[QOFF_ + (dq * 16 + dd) * 2]);
            s0 = fmaf(kv, q.x, s0);
            s1 = fmaf(kv, q.y, s1);
        }
        s0 += __shfl_xor(s0, 16, 64); s0 += __shfl_xor(s0, 32, 64);
        s1 += __shfl_xor(s1, 16, 64); s1 += __shfl_xor(s1, 32, 64);
        float mC = smem[MOFF2_ + tile * 16 + p16];
        float e0 = exp2f(s0 + mC);
        float e1 = exp2f(s1 + mC);
        if (dq == 0)
            *reinterpret_cast<float2*>(&WR[EOFF_ + p16 * 2]) = make_float2(e0, e1);

        // ---- PV: lane = dim; e broadcast; conflict-free V reads
        #pragma unroll
        for (int pp = 0; pp < 16; pp++) {
            float2 e = *reinterpret_cast<const float2*>(&WR[EOFF_ + pp * 2]);
            float  v = WR[VOFF_ + pp * 64 + l];
            ctx0 = fmaf(e.x, v, ctx0);
            ctx1 = fmaf(e.y, v, ctx1);
            lw0 += e.x; lw1 += e.y;
        }
    }

    // ---- per-wave acc into own (now dead) region
    WR[l]      = ctx0;
    WR[64 + l] = ctx1;
    if (l == 0) { WR[128] = lw0; WR[129] = lw1; }

    // ---- 2 new tokens (chunk 3, wave 0, lanes 0..31: dq = position)
    if (chunk == 3 && w == 0 && dq < 2) {
        const float* kn_b = knew + (nb * H_ + h) * (T_ * D_);
        const float* vn_b = vnew + (nb * H_ + h) * (T_ * D_);
        const int d0 = p16 * 4;
        float4 kfn = *reinterpret_cast<const float4*>(kn_b + dq * 64 + d0);
        float s0 = 0.f, s1 = 0.f;
        #pragma unroll
        for (int j = 0; j < 4; j++) {
            float2 q = *reinterpret_cast<const float2*>(&smem[QOFF_ + (d0 + j) * 2]);
            float kv = (j == 0) ? kfn.x : (j == 1) ? kfn.y : (j == 2) ? kfn.z : kfn.w;
            s0 = fmaf(kv, q.x, s0);
            s1 = fmaf(kv, q.y, s1);
        }
        #pragma unroll
        for (int off = 1; off < 16; off <<= 1) {
            s0 += __shfl_xor(s0, off, 64);
            s1 += __shfl_xor(s1, off, 64);
        }
        float mC = smem[MOFF2_ + CPOS2_ + dq];
        float e0 = exp2f(s0 + mC);
        float e1 = exp2f(s1 + mC);
        float4 vfn = *reinterpret_cast<const float4*>(vn_b + dq * 64 + d0);
        smem[TBOFF_ + (dq * 2 + 0) * 64 + d0 + 0] = e0 * vfn.x;
        smem[TBOFF_ + (dq * 2 + 0) * 64 + d0 + 1] = e0 * vfn.y;
        smem[TBOFF_ + (dq * 2 + 0) * 64 + d0 + 2] = e0 * vfn.z;
        smem[TBOFF_ + (dq * 2 + 0) * 64 + d0 + 3] = e0 * vfn.w;
        smem[TBOFF_ + (dq * 2 + 1) * 64 + d0 + 0] = e1 * vfn.x;
        smem[TBOFF_ + (dq * 2 + 1) * 64 + d0 + 1] = e1 * vfn.y;
        smem[TBOFF_ + (dq * 2 + 1) * 64 + d0 + 2] = e1 * vfn.z;
        smem[TBOFF_ + (dq * 2 + 1) * 64 + d0 + 3] = e1 * vfn.w;
        if (p16 == 0) {
            smem[LTOFF_ + dq * 2 + 0] = e0;
            smem[LTOFF_ + dq * 2 + 1] = e1;
        }
    }
    __syncthreads();

    // ---- cross-wave (+tail) reduction and write
    if (tid < 128) {
        const int t = tid >> 6, d = tid & 63;
        float s = 0.f, lv = 0.f;
        #pragma unroll
        for (int w2 = 0; w2 < 4; w2++) {
            s  += smem[w2 * PERW_ + t * 64 + d];
            lv += smem[w2 * PERW_ + 128 + t];
        }
        if (chunk == 3) {
            s  += smem[TBOFF_ + (0 * 2 + t) * 64 + d]
                + smem[TBOFF_ + (1 * 2 + t) * 64 + d];
            lv += smem[LTOFF_ + 0 * 2 + t] + smem[LTOFF_ + 1 * 2 + t];
        }
        cur_ctx[(u * 2 + t) * 64 + d] = s;
        if (d == 0) cur_l[u * 2 + t] = lv;
    }
}

// ---------------------------------------------------------------------------
// Prefix partial: 1024 blocks x 256 thr (R8 proven).
// ---------------------------------------------------------------------------
__global__ __launch_bounds__(256) void pfx_partial_kernel(
    const float* __restrict__ mask,   // [NB][TOT_]
    const float* __restrict__ pfx_k,  // [N][H][S][D]
    const float* __restrict__ pfx_v,
    const float* __restrict__ qT,     // [1024][64]
    float* __restrict__ pfx_ctx,      // [PFXU_][16][64]
    float* __restrict__ pfx_l)        // [PFXU_][16]
{
    __shared__ float smem[4160];
    const int tid = threadIdx.x;

    const int v     = blockIdx.x;
    const int n     = v >> 8;
    const int h     = (v >> 4) & 15;
    const int chunk = v & 15;
    const int wv    = tid >> 6;
    const int lane  = tid & 63;
    const int r     = lane & 15;
    const int c     = lane >> 4;

    float qreg[16];
    const float* qbase = qT + (h * 64 + c * 16) * 64 + (n * 16 + r);
    #pragma unroll
    for (int u = 0; u < 16; u++) qreg[u] = qbase[u * 64] * QS_;

    const size_t pos0 = (size_t)(n * H_ + h) * S_ + chunk * PLEN_;
    const float* kb = pfx_k + pos0 * D_;
    const float* vb = pfx_v + pos0 * D_;
    const float* mrow = mask + (n * 8 + (r >> 1)) * TOT_ + chunk * PLEN_;

    float ctx[16];
    #pragma unroll
    for (int u = 0; u < 16; u++) ctx[u] = 0.f;
    float lsum = 0.f;

    GLOAD_LDS16(kb + tid * 4, &smem[tid * 4]);
    GLOAD_LDS16(vb + tid * 4, &smem[1024 + tid * 4]);

    #pragma unroll 1
    for (int t = 0; t < NT_; t++) {
        const int bufo = (t & 1) * 2048;
        __syncthreads();

        float mreg[4];
        #pragma unroll
        for (int j = 0; j < 4; j++)
            mreg[j] = mrow[t * 16 + wv * 4 + j] * LOG2E_;

        if (t < NT_ - 1) {
            const int nbo = ((t + 1) & 1) * 2048;
            const float* kn = kb + (size_t)(t + 1) * 16 * 64;
            const float* vn = vb + (size_t)(t + 1) * 16 * 64;
            GLOAD_LDS16(kn + tid * 4, &smem[nbo + tid * 4]);
            GLOAD_LDS16(vn + tid * 4, &smem[nbo + 1024 + tid * 4]);
        }

        #pragma unroll
        for (int j = 0; j < 4; j++) {
            const int pp = wv * 4 + j;
            const float4* kq = reinterpret_cast<const float4*>(
                &smem[bufo + pp * 64 + c * 16]);
            float4 k0 = kq[0], k1 = kq[1], k2 = kq[2], k3 = kq[3];
            float sA = qreg[0]*k0.x;  sA = fmaf(qreg[1],k0.y,sA);
            sA = fmaf(qreg[2],k0.z,sA); sA = fmaf(qreg[3],k0.w,sA);
            float sB = qreg[4]*k1.x;  sB = fmaf(qreg[5],k1.y,sB);
            sB = fmaf(qreg[6],k1.z,sB); sB = fmaf(qreg[7],k1.w,sB);
            float sC = qreg[8]*k2.x;  sC = fmaf(qreg[9],k2.y,sC);
            sC = fmaf(qreg[10],k2.z,sC); sC = fmaf(qreg[11],k2.w,sC);
            float sD = qreg[12]*k3.x; sD = fmaf(qreg[13],k3.y,sD);
            sD = fmaf(qreg[14],k3.z,sD); sD = fmaf(qreg[15],k3.w,sD);
            float s = (sA + sB) + (sC + sD);
            s += __shfl_xor(s, 16, 64);
            s += __shfl_xor(s, 32, 64);
            float e = exp2f(s + mreg[j]);
            lsum += e;
            const float4* vq = reinterpret_cast<const float4*>(
                &smem[bufo + 1024 + pp * 64 + c * 16]);
            float4 v0 = vq[0], v1 = vq[1], v2 = vq[2], v3 = vq[3];
            ctx[0]  += e * v0.x; ctx[1]  += e * v0.y; ctx[2]  += e * v0.z; ctx[3]  += e * v0.w;
            ctx[4]  += e * v1.x; ctx[5]  += e * v1.y; ctx[6]  += e * v1.z; ctx[7]  += e * v1.w;
            ctx[8]  += e * v2.x; ctx[9]  += e * v2.y; ctx[10] += e * v2.z; ctx[11] += e * v2.w;
            ctx[12] += e * v3.x; ctx[13] += e * v3.y; ctx[14] += e * v3.z; ctx[15] += e * v3.w;
        }
    }

    __syncthreads();
    const int base = wv * 1024 + r * 64 + c * 16;
    #pragma unroll
    for (int u = 0; u < 16; u += 4)
        *reinterpret_cast<float4*>(&smem[base + u]) =
            make_float4(ctx[u], ctx[u+1], ctx[u+2], ctx[u+3]);
    if (c == 0) smem[4096 + wv * 16 + r] = lsum;
    __syncthreads();

    const int pc = (n * H_ + h) * PCH_ + chunk;
    for (int e = tid; e < 1024; e += 256) {
        float s = smem[e] + smem[1024 + e] + smem[2048 + e] + smem[3072 + e];
        pfx_ctx[pc * 1024 + e] = s;
    }
    if (tid < 16) {
        float l = smem[4096 + tid] + smem[4096 + 16 + tid]
                + smem[4096 + 32 + tid] + smem[4096 + 48 + tid];
        pfx_l[pc * 16 + tid] = l;
    }
}

// ---------------------------------------------------------------------------
// Combine: out = (sum of 4 cur + 16 prefix ctx partials) / (sum of l)
// ---------------------------------------------------------------------------
__global__ __launch_bounds__(256) void combine_kernel(
    const float* __restrict__ cur_ctx, const float* __restrict__ cur_l,
    const float* __restrict__ pfx_ctx, const float* __restrict__ pfx_l,
    float* __restrict__ out)
{
    const int row = blockIdx.x >> 2;      // nb*2+t
    const int qtr = blockIdx.x & 3;
    const int nb  = row >> 1, t = row & 1;
    const int n   = nb >> 3;
    const int r   = (nb & 7) * 2 + t;
    const int e   = qtr * 256 + threadIdx.x;   // h*64+d
    const int h   = e >> 6, d = e & 63;
    const int b   = nb * 16 + h;

    float val = 0.f, l = 0.f;
    #pragma unroll
    for (int ch = 0; ch < CCH2_; ch++) {
        int cb = b * CCH2_ + ch;
        val += cur_ctx[(cb * 2 + t) * 64 + d];
        l   += cur_l[cb * 2 + t];
    }
    #pragma unroll
    for (int ch = 0; ch < PCH_; ch++) {
        int pc = (n * H_ + h) * PCH_ + ch;
        val += pfx_ctx[pc * 1024 + r * 64 + d];
        l   += pfx_l[pc * 16 + r];
    }
    out[row * 1024 + e] = val / l;
}

extern "C" void kernel_launch(void* const* d_in, const int* in_sizes, int n_in,
                              void* d_out, int out_size, void* d_ws, size_t ws_size,
                              hipStream_t stream) {
    const float* hidden = (const float*)d_in[0];
    const float* mask   = (const float*)d_in[1];
    const float* pfxk   = (const float*)d_in[2];
    const float* pfxv   = (const float*)d_in[3];
    const float* pk     = (const float*)d_in[4];
    const float* pv     = (const float*)d_in[5];
    const float* Wq     = (const float*)d_in[6];
    const float* bq     = (const float*)d_in[7];
    const float* Wk     = (const float*)d_in[8];
    const float* bk     = (const float*)d_in[9];
    const float* Wv     = (const float*)d_in[10];
    const float* bv     = (const float*)d_in[11];

    float* qT      = (float*)d_ws;             // 65536
    float* knew    = qT + 65536;               // 65536
    float* vnew    = knew + 65536;             // 65536
    float* cur_ctx = vnew + 65536;             // 2048*2*64 = 262144
    float* cur_l   = cur_ctx + 262144;         // 4096
    float* pfx_ctx = cur_l + 4096;             // 1024*1024 = 1048576
    float* pfx_l   = pfx_ctx + 1048576;        // 16384

    qkv_kernel<<<384, 256, 0, stream>>>(hidden, Wq, bq, Wk, bk, Wv, bv,
                                        qT, knew, vnew);
    cur_gemm_kernel<<<NB_ * H_ * CCH2_, 256, 0, stream>>>(
        mask, pk, pv, qT, knew, vnew, cur_ctx, cur_l);
    pfx_partial_kernel<<<PFXU_, 256, 0, stream>>>(
        mask, pfxk, pfxv, qT, pfx_ctx, pfx_l);
    combine_kernel<<<256, 256, 0, stream>>>(cur_ctx, cur_l, pfx_ctx, pfx_l,
                                            (float*)d_out);
}

// Round 16
// 104.324 us; speedup vs baseline: 1.0719x; 1.0266x over previous
//
#include <hip/hip_runtime.h>
#include <hip/hip_bf16.h>

// N=4,B=8,T=2,E=1024,H=16,D=64,S=2048,L=1024
#define NB_  32
#define T_   2
#define E_   1024
#define H_   16
#define D_   64
#define S_   2048
#define L_   1024
#define TOT_ (S_ + L_ + T_)   // 3074

#define PCH_  16              // prefix chunks per (n,h): 128 pos each
#define PLEN_ (S_ / PCH_)     // 128
#define NT_   8               // tiles per prefix unit (16 pos each)
#define CCH_  8               // cur chunks per (nb,h): 128 pos each
#define CLEN_ (L_ / CCH_)     // 128

#define PFXBLK_ (4 * H_ * PCH_)   // 1024 prefix blocks
#define CURBLK_ (NB_ * H_ * CCH_) // 4096 cur blocks
#define PFXU_ PFXBLK_
#define CURU_ CURBLK_

#define LOG2E_ 1.4426950408889634f
#define QS_ (0.125f * LOG2E_)

#define GLOAD_LDS16(g, l) __builtin_amdgcn_global_load_lds( \
    (const __attribute__((address_space(1))) void*)(g), \
    (__attribute__((address_space(3))) void*)(l), 16, 0, 0)

// ---------------------------------------------------------------------------
// QKV: out[64][3072] = hidden[64][1024] @ Wcat^T + bias. (R8 proven)
// ---------------------------------------------------------------------------
__global__ __launch_bounds__(256) void qkv_kernel(
    const float* __restrict__ hidden,
    const float* __restrict__ Wq, const float* __restrict__ bq,
    const float* __restrict__ Wk, const float* __restrict__ bk,
    const float* __restrict__ Wv, const float* __restrict__ bv,
    float* __restrict__ qT,      // [1024][64]
    float* __restrict__ knew,    // [NB][H][T][D]
    float* __restrict__ vnew)
{
    __shared__ float ldsT[128 * 65];
    __shared__ float wlds[8 * 128];
    const int tid  = threadIdx.x;
    const int wave = tid >> 6;
    const int lane = tid & 63;
    const int eg0  = blockIdx.x * 8;
    const int mat  = eg0 >> 10;
    const int e0   = eg0 & 1023;
    int c0 = wave * 2;
    c0 = __builtin_amdgcn_readfirstlane(c0);

    const float* W    = (mat == 0) ? Wq : (mat == 1) ? Wk : Wv;
    const float* bias = (mat == 0) ? bq : (mat == 1) ? bk : bv;

    float aA0 = 0.f, aB0 = 0.f, aA1 = 0.f, aB1 = 0.f;

    for (int k0 = 0; k0 < 1024; k0 += 128) {
        __syncthreads();
        #pragma unroll
        for (int i = 0; i < 32; i++) {
            int f = i * 256 + tid;
            int r = f >> 7;
            int c = f & 127;
            ldsT[c * 65 + r] = hidden[r * 1024 + k0 + c];
        }
        {
            int wr = tid >> 5;
            int wc = (tid & 31) * 4;
            *reinterpret_cast<float4*>(&wlds[wr * 128 + wc]) =
                *reinterpret_cast<const float4*>(&W[(size_t)(e0 + wr) * 1024 + k0 + wc]);
        }
        __syncthreads();

        for (int kk = 0; kk < 128; kk += 4) {
            float h0 = ldsT[(kk + 0) * 65 + lane];
            float h1 = ldsT[(kk + 1) * 65 + lane];
            float h2 = ldsT[(kk + 2) * 65 + lane];
            float h3 = ldsT[(kk + 3) * 65 + lane];
            float4 w0 = *reinterpret_cast<const float4*>(&wlds[(c0 + 0) * 128 + kk]);
            float4 w1 = *reinterpret_cast<const float4*>(&wlds[(c0 + 1) * 128 + kk]);
            aA0 = fmaf(h0, w0.x, aA0); aA0 = fmaf(h1, w0.y, aA0);
            aB0 = fmaf(h2, w0.z, aB0); aB0 = fmaf(h3, w0.w, aB0);
            aA1 = fmaf(h0, w1.x, aA1); aA1 = fmaf(h1, w1.y, aA1);
            aB1 = fmaf(h2, w1.z, aB1); aB1 = fmaf(h3, w1.w, aB1);
        }
    }

    const int r = lane;
    #pragma unroll
    for (int j = 0; j < 2; j++) {
        int e_in = e0 + c0 + j;
        float val = ((j == 0) ? (aA0 + aB0) : (aA1 + aB1)) + bias[e_in];
        if (mat == 0) {
            qT[e_in * 64 + r] = val;
        } else {
            int nb = r >> 1, t = r & 1, h = e_in >> 6, d = e_in & 63;
            float* dst = (mat == 1) ? knew : vnew;
            dst[((nb * H_ + h) * T_ + t) * D_ + d] = val;
        }
    }
}

// ---------------------------------------------------------------------------
// Partial attention. 5120 one-shot blocks x 256 thr, prefix blocks first.
//  [0,1024):    prefix (n,h,chunk16): 128 pos in 8 LDS-staged tiles of 16
//               via double-buffered global_load_lds (16-way broadcast reuse).
//  [1024,5120): cur (nb,h,chunk8): 128 pos, register stream, all unit loads
//               issued up-front. (Session-best config: merged dispatch lets
//               prefix's L2-served traffic overlap the cur HBM stream.)
// No-max exp2 softmax -> unnormalized (ctx,l) partials add in combine.
// ---------------------------------------------------------------------------
__global__ __launch_bounds__(256) void partial_kernel(
    const float* __restrict__ mask,   // [NB][TOT_]
    const float* __restrict__ pfx_k,  // [N][H][S][D]
    const float* __restrict__ pfx_v,
    const float* __restrict__ pk,     // [NB][H][L][D]
    const float* __restrict__ pv,
    const float* __restrict__ qT,     // [1024][64]
    const float* __restrict__ knew,   // [NB][H][T][D]
    const float* __restrict__ vnew,
    float* __restrict__ cur_ctx,      // [CURU_][2][64]
    float* __restrict__ cur_l,        // [CURU_][2]
    float* __restrict__ pfx_ctx,      // [PFXU_][16][64]
    float* __restrict__ pfx_l)        // [PFXU_][16]
{
    __shared__ float smem[4160];
    const int tid = threadIdx.x;

    if (blockIdx.x < PFXBLK_) {
        // ================= prefix path (R8 proven) =================
        const int v     = blockIdx.x;
        const int n     = v >> 8;             // /(H_*PCH_)=256
        const int h     = (v >> 4) & 15;
        const int chunk = v & 15;
        const int wv    = tid >> 6;
        const int lane  = tid & 63;
        const int r     = lane & 15;          // row = beam*2 + t
        const int c     = lane >> 4;          // dim quarter

        float qreg[16];
        const float* qbase = qT + (h * 64 + c * 16) * 64 + (n * 16 + r);
        #pragma unroll
        for (int u = 0; u < 16; u++) qreg[u] = qbase[u * 64] * QS_;

        const size_t pos0 = (size_t)(n * H_ + h) * S_ + chunk * PLEN_;
        const float* kb = pfx_k + pos0 * D_;           // tile t: +t*16*64
        const float* vb = pfx_v + pos0 * D_;
        const float* mrow = mask + (n * 8 + (r >> 1)) * TOT_ + chunk * PLEN_;

        float ctx[16];
        #pragma unroll
        for (int u = 0; u < 16; u++) ctx[u] = 0.f;
        float lsum = 0.f;

        // stage tile 0 into buffer 0
        GLOAD_LDS16(kb + tid * 4, &smem[tid * 4]);
        GLOAD_LDS16(vb + tid * 4, &smem[1024 + tid * 4]);

        #pragma unroll 1
        for (int t = 0; t < NT_; t++) {
            const int bufo = (t & 1) * 2048;
            __syncthreads();   // drains this tile's gloads (vmcnt0 at barrier)

            // preload this tile's mask values (older than next gloads)
            float mreg[4];
            #pragma unroll
            for (int j = 0; j < 4; j++)
                mreg[j] = mrow[t * 16 + wv * 4 + j] * LOG2E_;

            if (t < NT_ - 1) {   // issue next tile into other buffer
                const int nbo = ((t + 1) & 1) * 2048;
                const float* kn = kb + (size_t)(t + 1) * 16 * 64;
                const float* vn = vb + (size_t)(t + 1) * 16 * 64;
                GLOAD_LDS16(kn + tid * 4, &smem[nbo + tid * 4]);
                GLOAD_LDS16(vn + tid * 4, &smem[nbo + 1024 + tid * 4]);
            }

            // compute 4 positions per wave from LDS
            #pragma unroll
            for (int j = 0; j < 4; j++) {
                const int pp = wv * 4 + j;
                const float4* kq = reinterpret_cast<const float4*>(
                    &smem[bufo + pp * 64 + c * 16]);
                float4 k0 = kq[0], k1 = kq[1], k2 = kq[2], k3 = kq[3];
                float sA = qreg[0]*k0.x;  sA = fmaf(qreg[1],k0.y,sA);
                sA = fmaf(qreg[2],k0.z,sA); sA = fmaf(qreg[3],k0.w,sA);
                float sB = qreg[4]*k1.x;  sB = fmaf(qreg[5],k1.y,sB);
                sB = fmaf(qreg[6],k1.z,sB); sB = fmaf(qreg[7],k1.w,sB);
                float sC = qreg[8]*k2.x;  sC = fmaf(qreg[9],k2.y,sC);
                sC = fmaf(qreg[10],k2.z,sC); sC = fmaf(qreg[11],k2.w,sC);
                float sD = qreg[12]*k3.x; sD = fmaf(qreg[13],k3.y,sD);
                sD = fmaf(qreg[14],k3.z,sD); sD = fmaf(qreg[15],k3.w,sD);
                float s = (sA + sB) + (sC + sD);
                s += __shfl_xor(s, 16, 64);
                s += __shfl_xor(s, 32, 64);
                float e = exp2f(s + mreg[j]);
                lsum += e;
                const float4* vq = reinterpret_cast<const float4*>(
                    &smem[bufo + 1024 + pp * 64 + c * 16]);
                float4 v0 = vq[0], v1 = vq[1], v2 = vq[2], v3 = vq[3];
                ctx[0]  += e * v0.x; ctx[1]  += e * v0.y; ctx[2]  += e * v0.z; ctx[3]  += e * v0.w;
                ctx[4]  += e * v1.x; ctx[5]  += e * v1.y; ctx[6]  += e * v1.z; ctx[7]  += e * v1.w;
                ctx[8]  += e * v2.x; ctx[9]  += e * v2.y; ctx[10] += e * v2.z; ctx[11] += e * v2.w;
                ctx[12] += e * v3.x; ctx[13] += e * v3.y; ctx[14] += e * v3.z; ctx[15] += e * v3.w;
            }
        }

        __syncthreads();   // stage buffers dead; reuse smem as sred
        const int base = wv * 1024 + r * 64 + c * 16;
        #pragma unroll
        for (int u = 0; u < 16; u += 4)
            *reinterpret_cast<float4*>(&smem[base + u]) =
                make_float4(ctx[u], ctx[u+1], ctx[u+2], ctx[u+3]);
        if (c == 0) smem[4096 + wv * 16 + r] = lsum;
        __syncthreads();

        const int pc = (n * H_ + h) * PCH_ + chunk;
        for (int e = tid; e < 1024; e += 256) {
            float s = smem[e] + smem[1024 + e] + smem[2048 + e] + smem[3072 + e];
            pfx_ctx[pc * 1024 + e] = s;
        }
        if (tid < 16) {
            float l = smem[4096 + tid] + smem[4096 + 16 + tid]
                    + smem[4096 + 32 + tid] + smem[4096 + 48 + tid];
            pfx_l[pc * 16 + tid] = l;
        }
    } else {
        // ================= cur path: depth-8 register pipeline =============
        const int u     = blockIdx.x - PFXBLK_;   // 0..4095
        const int b     = u >> 3;                  // nb*16+h
        const int chunk = u & 7;
        const int nb    = b >> 4;
        const int h     = b & 15;
        const int g     = tid >> 4;     // group 0..15
        const int l16   = tid & 15;
        const int d0    = l16 * 4;

        float qf0[4], qf1[4];
        #pragma unroll
        for (int j = 0; j < 4; j++) {
            const float* qb = qT + (h * 64 + d0 + j) * 64 + nb * 2;
            qf0[j] = qb[0] * QS_;
            qf1[j] = qb[1] * QS_;
        }

        const float* pk_b = pk + ((nb * H_ + h) * (size_t)L_) * D_;
        const float* pv_b = pv + ((nb * H_ + h) * (size_t)L_) * D_;
        const float* mrow = mask + nb * TOT_ + S_;
        const int p0 = chunk * CLEN_ + g;

        // masks first (their vmcnt retires before the big K/V batch)
        float mreg[8];
        #pragma unroll
        for (int i = 0; i < 8; i++) mreg[i] = mrow[p0 + i * 16] * LOG2E_;

        // issue ALL unit loads (static arrays)
        float4 kf[8], vf[8];
        #pragma unroll
        for (int i = 0; i < 8; i++) {
            kf[i] = *reinterpret_cast<const float4*>(pk_b + (size_t)(p0 + i * 16) * D_ + d0);
            vf[i] = *reinterpret_cast<const float4*>(pv_b + (size_t)(p0 + i * 16) * D_ + d0);
        }

        float l0 = 0.f, l1 = 0.f;
        float a0[4] = {0.f,0.f,0.f,0.f};
        float a1[4] = {0.f,0.f,0.f,0.f};

        #pragma unroll
        for (int i = 0; i < 8; i++) {
            float s0 = fmaf(qf0[0],kf[i].x, qf0[1]*kf[i].y) + fmaf(qf0[2],kf[i].z, qf0[3]*kf[i].w);
            float s1 = fmaf(qf1[0],kf[i].x, qf1[1]*kf[i].y) + fmaf(qf1[2],kf[i].z, qf1[3]*kf[i].w);
            #pragma unroll
            for (int off = 1; off < 16; off <<= 1) {
                s0 += __shfl_xor(s0, off, 64);
                s1 += __shfl_xor(s1, off, 64);
            }
            float e0 = exp2f(s0 + mreg[i]);
            float e1 = exp2f(s1 + mreg[i]);
            l0 += e0; l1 += e1;
            a0[0] += e0 * vf[i].x; a0[1] += e0 * vf[i].y; a0[2] += e0 * vf[i].z; a0[3] += e0 * vf[i].w;
            a1[0] += e1 * vf[i].x; a1[1] += e1 * vf[i].y; a1[2] += e1 * vf[i].z; a1[3] += e1 * vf[i].w;
        }

        if (chunk == 7 && g < 2) {                // 2 new tokens
            const float* kn_b = knew + (nb * H_ + h) * (T_ * D_);
            const float* vn_b = vnew + (nb * H_ + h) * (T_ * D_);
            float4 kfn = *reinterpret_cast<const float4*>(kn_b + g * D_ + d0);
            float s0 = fmaf(qf0[0],kfn.x, qf0[1]*kfn.y) + fmaf(qf0[2],kfn.z, qf0[3]*kfn.w);
            float s1 = fmaf(qf1[0],kfn.x, qf1[1]*kfn.y) + fmaf(qf1[2],kfn.z, qf1[3]*kfn.w);
            #pragma unroll
            for (int off = 1; off < 16; off <<= 1) {
                s0 += __shfl_xor(s0, off, 64);
                s1 += __shfl_xor(s1, off, 64);
            }
            float mC = mrow[L_ + g] * LOG2E_;
            float e0 = exp2f(s0 + mC);
            float e1 = exp2f(s1 + mC);
            l0 += e0; l1 += e1;
            float4 vfn = *reinterpret_cast<const float4*>(vn_b + g * D_ + d0);
            a0[0] += e0 * vfn.x; a0[1] += e0 * vfn.y; a0[2] += e0 * vfn.z; a0[3] += e0 * vfn.w;
            a1[0] += e1 * vfn.x; a1[1] += e1 * vfn.y; a1[2] += e1 * vfn.z; a1[3] += e1 * vfn.w;
        }

        #pragma unroll
        for (int j = 0; j < 4; j++) {
            smem[g * 128 + d0 + j]      = a0[j];
            smem[g * 128 + 64 + d0 + j] = a1[j];
        }
        if (l16 == 0) { smem[2048 + g * 2] = l0; smem[2048 + g * 2 + 1] = l1; }
        __syncthreads();

        if (tid < 128) {
            int t = tid >> 6, d = tid & 63;
            float s = 0.f, l = 0.f;
            for (int g2 = 0; g2 < 16; g2++) {
                s += smem[g2 * 128 + t * 64 + d];
                l += smem[2048 + g2 * 2 + t];
            }
            cur_ctx[(u * 2 + t) * 64 + d] = s;
            if (d == 0) cur_l[u * 2 + t] = l;
        }
    }
}

// ---------------------------------------------------------------------------
// Combine: out = (sum of 8 cur + 16 prefix ctx partials) / (sum of l)
// ---------------------------------------------------------------------------
__global__ __launch_bounds__(256) void combine_kernel(
    const float* __restrict__ cur_ctx, const float* __restrict__ cur_l,
    const float* __restrict__ pfx_ctx, const float* __restrict__ pfx_l,
    float* __restrict__ out)
{
    const int row = blockIdx.x >> 2;      // nb*2+t
    const int qtr = blockIdx.x & 3;
    const int nb  = row >> 1, t = row & 1;
    const int n   = nb >> 3;
    const int r   = (nb & 7) * 2 + t;
    const int e   = qtr * 256 + threadIdx.x;   // h*64+d
    const int h   = e >> 6, d = e & 63;
    const int b   = nb * 16 + h;

    float val = 0.f, l = 0.f;
    #pragma unroll
    for (int ch = 0; ch < CCH_; ch++) {
        int cb = (b * CCH_ + ch);
        val += cur_ctx[(cb * 2 + t) * 64 + d];
        l   += cur_l[cb * 2 + t];
    }
    #pragma unroll
    for (int ch = 0; ch < PCH_; ch++) {
        int pc = (n * H_ + h) * PCH_ + ch;
        val += pfx_ctx[pc * 1024 + r * 64 + d];
        l   += pfx_l[pc * 16 + r];
    }
    out[row * 1024 + e] = val / l;
}

extern "C" void kernel_launch(void* const* d_in, const int* in_sizes, int n_in,
                              void* d_out, int out_size, void* d_ws, size_t ws_size,
                              hipStream_t stream) {
    const float* hidden = (const float*)d_in[0];
    const float* mask   = (const float*)d_in[1];
    const float* pfxk   = (const float*)d_in[2];
    const float* pfxv   = (const float*)d_in[3];
    const float* pk     = (const float*)d_in[4];
    const float* pv     = (const float*)d_in[5];
    const float* Wq     = (const float*)d_in[6];
    const float* bq     = (const float*)d_in[7];
    const float* Wk     = (const float*)d_in[8];
    const float* bk     = (const float*)d_in[9];
    const float* Wv     = (const float*)d_in[10];
    const float* bv     = (const float*)d_in[11];

    float* qT      = (float*)d_ws;             // 65536
    float* knew    = qT + 65536;               // 65536
    float* vnew    = knew + 65536;             // 65536
    float* cur_ctx = vnew + 65536;             // 4096*2*64 = 524288
    float* cur_l   = cur_ctx + 524288;         // 8192
    float* pfx_ctx = cur_l + 8192;             // 1024*1024 = 1048576
    float* pfx_l   = pfx_ctx + 1048576;        // 16384

    qkv_kernel<<<384, 256, 0, stream>>>(hidden, Wq, bq, Wk, bk, Wv, bv,
                                        qT, knew, vnew);
    partial_kernel<<<PFXBLK_ + CURBLK_, 256, 0, stream>>>(
        mask, pfxk, pfxv, pk, pv, qT, knew, vnew,
        cur_ctx, cur_l, pfx_ctx, pfx_l);
    combine_kernel<<<256, 256, 0, stream>>>(cur_ctx, cur_l, pfx_ctx, pfx_l,
                                            (float*)d_out);
}